// Round 20
// baseline (53.598 us; speedup 1.0000x reference)
//
#include <hip/hip_runtime.h>
#include <math.h>

constexpr int D  = 768;
constexpr int NQ = 8;
constexpr int B  = 32;
constexpr int NP = 196;      // n_patch
constexpr int KT = 7;        // K tiles of 32
constexpr int TPAD = 776;    // LDS tile row stride (shorts)
constexpr int NTOFF = 28;    // off-diag 4x4-group tiles: C(8,2)
constexpr int NTILES = 32;   // + 4 diag-combo tiles (2 groups each)
constexpr float EPS = 1e-5f;
constexpr float INV_SQRT_D = 0.036084391824351615f;  // 1/sqrt(768)

typedef __attribute__((ext_vector_type(8))) short short8;
typedef __attribute__((ext_vector_type(4))) float f32x4;

__device__ __forceinline__ unsigned short f2bf(float x) {
    union { float f; unsigned u; } c; c.f = x;
    unsigned r = c.u + 0x7fffu + ((c.u >> 16) & 1u);   // RNE
    return (unsigned short)(r >> 16);
}

// Fused: LN(q)->qbf LDS + LN(kv 16-row half-tile) + MFMA scores S + frag pack.
// kvTf[b][dt:48][kt:7][slot:64][e:8], value = kvn[kt*32+kg*8+e][dt*16+dl].
// One block per (b, h), h in [0,14): rows [h*16, h*16+16).
__global__ __launch_bounds__(256, 4) void kv_fused(const float* __restrict__ q_x,
                                                   const float* __restrict__ qw,
                                                   const float* __restrict__ qb,
                                                   const float* __restrict__ kv_x,
                                                   const float* __restrict__ kw,
                                                   const float* __restrict__ kb,
                                                   float* __restrict__ S,
                                                   unsigned short* __restrict__ kvTf) {
    const int b = blockIdx.x / 14;
    const int h = blockIdx.x % 14;
    const int kt = h >> 1;
    const int kgbase = (h & 1) * 2;
    const int tid = threadIdx.x, wave = tid >> 6, lane = tid & 63;
    __shared__ unsigned short tile[16][TPAD];  // 24.8 KB (scores A-source)
    __shared__ unsigned short qbf[8][TPAD];    // 12.4 KB

    const bool live = (h * 16) < NP;

    float wv[12], bv[12];
#pragma unroll
    for (int c = 0; c < 12; ++c) { wv[c] = kw[lane + 64 * c]; bv[c] = kb[lane + 64 * c]; }

    // q-LN -> qbf (bf16): wave w handles q rows {2w, 2w+1}, batched.
    if (live && wave < 4) {
        float wq[12], bq[12];
#pragma unroll
        for (int c = 0; c < 12; ++c) { wq[c] = qw[lane + 64 * c]; bq[c] = qb[lane + 64 * c]; }
        float v0[12], v1[12];
        float s0 = 0.f, t0 = 0.f, s1 = 0.f, t1 = 0.f;
        const int q0 = wave * 2, q1 = q0 + 1;
#pragma unroll
        for (int c = 0; c < 12; ++c) {
            v0[c] = q_x[q0 * D + lane + 64 * c];
            v1[c] = q_x[q1 * D + lane + 64 * c];
            s0 += v0[c]; t0 = fmaf(v0[c], v0[c], t0);
            s1 += v1[c]; t1 = fmaf(v1[c], v1[c], t1);
        }
#pragma unroll
        for (int off = 32; off > 0; off >>= 1) {
            s0 += __shfl_xor(s0, off, 64);
            s1 += __shfl_xor(s1, off, 64);
            t0 += __shfl_xor(t0, off, 64);
            t1 += __shfl_xor(t1, off, 64);
        }
        const float m0 = s0 * (1.0f / D), m1 = s1 * (1.0f / D);
        const float r0 = rsqrtf(t0 * (1.0f / D) - m0 * m0 + EPS);
        const float r1 = rsqrtf(t1 * (1.0f / D) - m1 * m1 + EPS);
#pragma unroll
        for (int c = 0; c < 12; ++c) {
            qbf[q0][lane + 64 * c] = f2bf((v0[c] - m0) * r0 * wq[c] + bq[c]);
            qbf[q1][lane + 64 * c] = f2bf((v1[c] - m1) * r1 * wq[c] + bq[c]);
        }
    }

    // kv-LN -> tile (bf16) + register pack, rows 4w..4w+3 in 2 batches of 2.
    unsigned pk01[12], pk23[12];
#pragma unroll
    for (int b2 = 0; b2 < 2; ++b2) {
        const int nl0 = wave * 4 + 2 * b2;
        const int n0 = h * 16 + nl0, n1 = n0 + 1;
        const bool a0 = n0 < NP, a1 = n1 < NP;
        const float* x0 = kv_x + ((size_t)b * NP + n0) * D;
        const float* x1 = kv_x + ((size_t)b * NP + n1) * D;
        float v0[12], v1[12];
        float s0 = 0.f, t0 = 0.f, s1 = 0.f, t1 = 0.f;
#pragma unroll
        for (int c = 0; c < 12; ++c) {
            v0[c] = a0 ? x0[lane + 64 * c] : 0.f;
            v1[c] = a1 ? x1[lane + 64 * c] : 0.f;
            s0 += v0[c]; t0 = fmaf(v0[c], v0[c], t0);
            s1 += v1[c]; t1 = fmaf(v1[c], v1[c], t1);
        }
#pragma unroll
        for (int off = 32; off > 0; off >>= 1) {
            s0 += __shfl_xor(s0, off, 64);
            s1 += __shfl_xor(s1, off, 64);
            t0 += __shfl_xor(t0, off, 64);
            t1 += __shfl_xor(t1, off, 64);
        }
        const float m0 = s0 * (1.0f / D), m1 = s1 * (1.0f / D);
        const float r0 = rsqrtf(t0 * (1.0f / D) - m0 * m0 + EPS);
        const float r1 = rsqrtf(t1 * (1.0f / D) - m1 * m1 + EPS);
#pragma unroll
        for (int c = 0; c < 12; ++c) {
            const int d = lane + 64 * c;
            const unsigned short bf0 = a0 ? f2bf((v0[c] - m0) * r0 * wv[c] + bv[c]) : (unsigned short)0;
            const unsigned short bf1 = a1 ? f2bf((v1[c] - m1) * r1 * wv[c] + bv[c]) : (unsigned short)0;
            tile[nl0][d] = bf0;
            tile[nl0 + 1][d] = bf1;
            const unsigned packed = (unsigned)bf0 | ((unsigned)bf1 << 16);
            if (b2 == 0) pk01[c] = packed; else pk23[c] = packed;
        }
    }

    // direct frag store: 12 x 8B per thread, no LDS gather
    {
        const int kg = kgbase + (wave >> 1);
        const int eh = (wave & 1);
        const int dl = lane & 15;
#pragma unroll
        for (int c = 0; c < 12; ++c) {
            const int dt = (lane >> 4) + 4 * c;
            uint2 val; val.x = pk01[c]; val.y = pk23[c];
            *(uint2*)(kvTf + ((((size_t)b * 48 + dt) * KT + kt) * 64 + kg * 16 + dl) * 8 + eh * 4) = val;
        }
    }
    __syncthreads();

    // scores via MFMA: S16x8 = tile(16 x 768) x qbf^T, wave 0 only.
    if (live && wave == 0) {
        f32x4 s0 = {0.f, 0.f, 0.f, 0.f}, s1 = {0.f, 0.f, 0.f, 0.f};
        const int ar = lane & 15, akg = lane >> 4;
        const int qr = ar & 7;
#pragma unroll
        for (int k2 = 0; k2 < 24; k2 += 2) {
            s0 = __builtin_amdgcn_mfma_f32_16x16x32_bf16(
                *(const short8*)&tile[ar][k2 * 32 + akg * 8],
                *(const short8*)&qbf[qr][k2 * 32 + akg * 8], s0, 0, 0, 0);
            s1 = __builtin_amdgcn_mfma_f32_16x16x32_bf16(
                *(const short8*)&tile[ar][(k2 + 1) * 32 + akg * 8],
                *(const short8*)&qbf[qr][(k2 + 1) * 32 + akg * 8], s1, 0, 0, 0);
        }
        s0 = s0 + s1;
        const int q = lane & 15;
        if (q < NQ) {
#pragma unroll
            for (int reg = 0; reg < 4; ++reg) {
                const int n = h * 16 + akg * 4 + reg;
                if (n < NP) S[((size_t)b * NQ + q) * NP + n] = s0[reg] * INV_SQRT_D;
            }
        }
    }
}

// dgemm v5b: 8-wave LDS-staged pair GEMM with in-register pair softmax.
// Same as v5 but the kt-loop is FORCE-UNROLLED and areg indexed statically
// (rule #20: the r19 version left a runtime select -> scratch spill).
// A-frags hold UNNORMALIZED bf16(exp(x-m)); 1/sum folded into the epilogue.
__global__ __launch_bounds__(512, 4) void dgemm(const float* __restrict__ S,
                                                const unsigned short* __restrict__ kvTf,
                                                float* __restrict__ out) {
    const int bid = blockIdx.x;
    const int t = bid >> 4, cs = bid & 15;   // XCD = bid%8 = cs%8
    const int tid = threadIdx.x, wave = tid >> 6, lane = tid & 63;

    __shared__ unsigned short stg[2][8][3][64][8];  // 48 KB double-buffered

    const bool offd = (t < NTOFF);
    int gi = 0, gj = 0;
    if (offd) {
        int tt = t, a = 0;
        while (tt >= 7 - a) { tt -= 7 - a; ++a; }
        gi = a; gj = a + 1 + tt;
    }
    const int dbase = 8 * (t - NTOFF);

    // ---- wave decode: 2 pairs, all 3 dt ----
    int i0 = 0, j0 = 0, i1 = 0, j1 = 0;
    int p0i = 0, p0j = 0, p1i = 0, p1j = 0;
    bool compute = true;
    if (offd) {
        const int pi = wave >> 1, bh = wave & 1;
        i0 = 4 * gi + pi; j0 = 4 * gj + 2 * bh;
        i1 = i0;          j1 = j0 + 1;
        p0i = pi; p0j = 4 + 2 * bh; p1i = pi; p1j = p0j + 1;
    } else if (wave < 6) {
        const int g = wave / 3, k3 = wave - 3 * g;
        const int ea[6] = {0, 0, 0, 1, 1, 2}, eb[6] = {1, 2, 3, 2, 3, 3};
        const int e0 = 2 * k3, e1 = e0 + 1;
        p0i = 4 * g + ea[e0]; p0j = 4 * g + eb[e0];
        p1i = 4 * g + ea[e1]; p1j = 4 * g + eb[e1];
        i0 = dbase + p0i; j0 = dbase + p0j;
        i1 = dbase + p1i; j1 = dbase + p1j;
    } else {
        compute = false;
        const int zw = wave - 6;
#pragma unroll
        for (int t2 = 0; t2 < 4; ++t2) {
            const int ii = dbase + zw * 4 + t2;
            float* base = out + (size_t)(ii * B + ii) * NQ * D + cs * 48;
#pragma unroll
            for (int rep = 0; rep < 6; ++rep) {
                const int e = rep * 64 + lane;
                const int q = e / 48, c = e - q * 48;
                base[q * D + c] = 0.f;
            }
        }
    }

    // ---- staging: issue kt=0 FIRST so it overlaps the softmax prologue ----
    const int sp = wave;
    const int sb = offd ? ((sp < 4) ? (4 * gi + sp) : (4 * gj + sp - 4)) : (dbase + sp);
    const unsigned short* gbase =
        kvTf + (((size_t)sb * 48 + cs * 3) * KT) * 512 + (size_t)lane * 8;

#pragma unroll
    for (int r = 0; r < 3; ++r)
        __builtin_amdgcn_global_load_lds(
            (const __attribute__((address_space(1))) void*)(gbase + ((size_t)r * KT) * 512),
            (__attribute__((address_space(3))) void*)(&stg[0][sp][r][0][0]), 16, 0, 0);

    // ---- in-register softmax for this wave's 2 pairs ----
    short8 areg0[KT], areg1[KT];
    float rinv0 = 1.f, rinv1 = 1.f;
    if (compute) {
        const int rr = lane & 15, kg = lane >> 4;
        const int dir = rr >> 3, q = rr & 7;
#pragma unroll
        for (int pr = 0; pr < 2; ++pr) {
            const int i = pr ? i1 : i0, j = pr ? j1 : j0;
            const float* Sa = S + (size_t)((dir ? j : i) * NQ + q) * NP;
            const float* Sb = S + (size_t)((dir ? i : j) * NQ + q) * NP;
            float m = -1e30f;
#pragma unroll
            for (int kt = 0; kt < KT; ++kt) {
                const int n0 = kt * 32 + kg * 8;
                if (n0 < NP) {
                    const f32x4 alo = *(const f32x4*)(Sa + n0);
                    const f32x4 ahi = *(const f32x4*)(Sa + n0 + 4);
                    const f32x4 blo = *(const f32x4*)(Sb + n0);
                    const f32x4 bhi = *(const f32x4*)(Sb + n0 + 4);
#pragma unroll
                    for (int e = 0; e < 4; ++e) {
                        if (n0 + e < NP)     m = fmaxf(m, alo[e] - blo[e]);
                        if (n0 + 4 + e < NP) m = fmaxf(m, ahi[e] - bhi[e]);
                    }
                }
            }
            m = fmaxf(m, __shfl_xor(m, 16, 64));
            m = fmaxf(m, __shfl_xor(m, 32, 64));
            float sum = 0.f;
#pragma unroll
            for (int kt = 0; kt < KT; ++kt) {
                const int n0 = kt * 32 + kg * 8;
                short8 pk = {0, 0, 0, 0, 0, 0, 0, 0};
                if (n0 < NP) {
                    const f32x4 alo = *(const f32x4*)(Sa + n0);
                    const f32x4 ahi = *(const f32x4*)(Sa + n0 + 4);
                    const f32x4 blo = *(const f32x4*)(Sb + n0);
                    const f32x4 bhi = *(const f32x4*)(Sb + n0 + 4);
#pragma unroll
                    for (int e = 0; e < 4; ++e) {
                        if (n0 + e < NP) {
                            const float ex = __expf(alo[e] - blo[e] - m);
                            sum += ex; pk[e] = (short)f2bf(ex);
                        }
                        if (n0 + 4 + e < NP) {
                            const float ex = __expf(ahi[e] - bhi[e] - m);
                            sum += ex; pk[e + 4] = (short)f2bf(ex);
                        }
                    }
                }
                if (pr == 0) areg0[kt] = pk; else areg1[kt] = pk;
            }
            sum += __shfl_xor(sum, 16, 64);
            sum += __shfl_xor(sum, 32, 64);
            if (pr == 0) rinv0 = 1.0f / sum; else rinv1 = 1.0f / sum;
        }
    }

    f32x4 acc0[3], acc1[3];
#pragma unroll
    for (int nf = 0; nf < 3; ++nf) {
        f32x4 z = {0.f, 0.f, 0.f, 0.f};
        acc0[nf] = z; acc1[nf] = z;
    }

    __syncthreads();

    int buf = 0;
#pragma unroll
    for (int kt = 0; kt < KT; ++kt) {       // FULL UNROLL: areg[kt] static
        if (kt + 1 < KT) {
#pragma unroll
            for (int r = 0; r < 3; ++r)
                __builtin_amdgcn_global_load_lds(
                    (const __attribute__((address_space(1))) void*)(gbase + ((size_t)r * KT + kt + 1) * 512),
                    (__attribute__((address_space(3))) void*)(&stg[buf ^ 1][sp][r][0][0]), 16, 0, 0);
        }
        if (compute) {
            const short8 a0 = areg0[kt], a1 = areg1[kt];
            short8 na0, na1;
#pragma unroll
            for (int e = 0; e < 8; ++e) {
                na0[e] = (short)(a0[e] ^ (short)0x8000);
                na1[e] = (short)(a1[e] ^ (short)0x8000);
            }
            if (offd) {  // shared ki: 9 ds_reads feed 12 MFMAs
#pragma unroll
                for (int nf = 0; nf < 3; ++nf) {
                    const short8 ki  = *(const short8*)(&stg[buf][p0i][nf][lane][0]);
                    const short8 kj0 = *(const short8*)(&stg[buf][p0j][nf][lane][0]);
                    const short8 kj1 = *(const short8*)(&stg[buf][p1j][nf][lane][0]);
                    acc0[nf] = __builtin_amdgcn_mfma_f32_16x16x32_bf16(a0,  ki,  acc0[nf], 0, 0, 0);
                    acc0[nf] = __builtin_amdgcn_mfma_f32_16x16x32_bf16(na0, kj0, acc0[nf], 0, 0, 0);
                    acc1[nf] = __builtin_amdgcn_mfma_f32_16x16x32_bf16(a1,  ki,  acc1[nf], 0, 0, 0);
                    acc1[nf] = __builtin_amdgcn_mfma_f32_16x16x32_bf16(na1, kj1, acc1[nf], 0, 0, 0);
                }
            } else {
#pragma unroll
                for (int nf = 0; nf < 3; ++nf) {
                    const short8 k0i = *(const short8*)(&stg[buf][p0i][nf][lane][0]);
                    const short8 k0j = *(const short8*)(&stg[buf][p0j][nf][lane][0]);
                    const short8 k1i = *(const short8*)(&stg[buf][p1i][nf][lane][0]);
                    const short8 k1j = *(const short8*)(&stg[buf][p1j][nf][lane][0]);
                    acc0[nf] = __builtin_amdgcn_mfma_f32_16x16x32_bf16(a0,  k0i, acc0[nf], 0, 0, 0);
                    acc0[nf] = __builtin_amdgcn_mfma_f32_16x16x32_bf16(na0, k0j, acc0[nf], 0, 0, 0);
                    acc1[nf] = __builtin_amdgcn_mfma_f32_16x16x32_bf16(a1,  k1i, acc1[nf], 0, 0, 0);
                    acc1[nf] = __builtin_amdgcn_mfma_f32_16x16x32_bf16(na1, k1j, acc1[nf], 0, 0, 0);
                }
            }
        }
        __syncthreads();
        buf ^= 1;
    }

    // ---- epilogue: scale by per-row 1/sum (broadcast from row's lane) ----
    if (compute) {
        const int kgrp = lane >> 4, dl = lane & 15;
        const int colb = cs * 48 + dl;
#pragma unroll
        for (int pr = 0; pr < 2; ++pr) {
            const int i = pr ? i1 : i0, j = pr ? j1 : j0;
            const f32x4* acc = pr ? acc1 : acc0;
            const float rinv = pr ? rinv1 : rinv0;
            const int pij = i * B + j, pji = j * B + i;
#pragma unroll
            for (int reg = 0; reg < 4; ++reg) {
                const int r = kgrp * 4 + reg;
                const float rv = __shfl(rinv, r, 64);
                const int dirr = r >> 3, qq = r & 7;
                const int p = dirr ? pji : pij;
                const float sgn = dirr ? -1.f : 1.f;
                float* op = out + ((size_t)p * NQ + qq) * D + colb;
#pragma unroll
                for (int nf = 0; nf < 3; ++nf) op[nf * 16] = sgn * rv * acc[nf][reg];
            }
        }
    }
}

extern "C" void kernel_launch(void* const* d_in, const int* in_sizes, int n_in,
                              void* d_out, int out_size, void* d_ws, size_t ws_size,
                              hipStream_t stream) {
    const float* q_x     = (const float*)d_in[0];
    const float* kv_x    = (const float*)d_in[1];
    const float* ln_q_w  = (const float*)d_in[2];
    const float* ln_q_b  = (const float*)d_in[3];
    const float* ln_kv_w = (const float*)d_in[4];
    const float* ln_kv_b = (const float*)d_in[5];
    float* out = (float*)d_out;

    float* ws = (float*)d_ws;
    float* S  = ws;                                             // 32*8*196 f32
    unsigned short* kvTf = (unsigned short*)(ws + B * NQ * NP);  // 32*48*7*512 bf16

    kv_fused<<<B * 14, 256, 0, stream>>>(q_x, ln_q_w, ln_q_b, kv_x, ln_kv_w, ln_kv_b, S, kvTf);
    dgemm<<<NTILES * 16, 512, 0, stream>>>(S, kvTf, out);
}

// Round 21
// 35.760 us; speedup vs baseline: 1.4988x; 1.4988x over previous
//
#include <hip/hip_runtime.h>
#include <math.h>

constexpr int D  = 768;
constexpr int NQ = 8;
constexpr int B  = 32;
constexpr int NP = 196;      // n_patch
constexpr int KT = 7;        // K tiles of 32
constexpr int KP = KT * 32;  // 224 padded K
constexpr int TPAD = 776;    // LDS tile row stride (shorts)
constexpr int NTOFF = 28;    // off-diag 4x4-group tiles: C(8,2)
constexpr int NTILES = 32;   // + 4 diag-combo tiles (2 groups each)
constexpr float EPS = 1e-5f;
constexpr float INV_SQRT_D = 0.036084391824351615f;  // 1/sqrt(768)

typedef __attribute__((ext_vector_type(8))) short short8;
typedef __attribute__((ext_vector_type(4))) float f32x4;

__device__ __forceinline__ float wave_reduce_sum(float v) {
#pragma unroll
    for (int off = 32; off > 0; off >>= 1) v += __shfl_xor(v, off, 64);
    return v;
}
__device__ __forceinline__ float wave_reduce_max(float v) {
#pragma unroll
    for (int off = 32; off > 0; off >>= 1) v = fmaxf(v, __shfl_xor(v, off, 64));
    return v;
}

__device__ __forceinline__ unsigned short f2bf(float x) {
    union { float f; unsigned u; } c; c.f = x;
    unsigned r = c.u + 0x7fffu + ((c.u >> 16) & 1u);   // RNE
    return (unsigned short)(r >> 16);
}

// Fused: LN(q)->qbf LDS + LN(kv 16-row half-tile) + MFMA scores S + frag pack.
// kvTf[b][dt:48][kt:7][slot:64][e:8], value = kvn[kt*32+kg*8+e][dt*16+dl].
// One block per (b, h), h in [0,14): rows [h*16, h*16+16).
__global__ __launch_bounds__(256, 4) void kv_fused(const float* __restrict__ q_x,
                                                   const float* __restrict__ qw,
                                                   const float* __restrict__ qb,
                                                   const float* __restrict__ kv_x,
                                                   const float* __restrict__ kw,
                                                   const float* __restrict__ kb,
                                                   float* __restrict__ S,
                                                   unsigned short* __restrict__ kvTf) {
    const int b = blockIdx.x / 14;
    const int h = blockIdx.x % 14;
    const int kt = h >> 1;
    const int kgbase = (h & 1) * 2;
    const int tid = threadIdx.x, wave = tid >> 6, lane = tid & 63;
    __shared__ unsigned short tile[16][TPAD];  // 24.8 KB (scores A-source)
    __shared__ unsigned short qbf[8][TPAD];    // 12.4 KB

    const bool live = (h * 16) < NP;

    float wv[12], bv[12];
#pragma unroll
    for (int c = 0; c < 12; ++c) { wv[c] = kw[lane + 64 * c]; bv[c] = kb[lane + 64 * c]; }

    // q-LN -> qbf (bf16): wave w handles q rows {2w, 2w+1}, batched.
    if (live && wave < 4) {
        float wq[12], bq[12];
#pragma unroll
        for (int c = 0; c < 12; ++c) { wq[c] = qw[lane + 64 * c]; bq[c] = qb[lane + 64 * c]; }
        float v0[12], v1[12];
        float s0 = 0.f, t0 = 0.f, s1 = 0.f, t1 = 0.f;
        const int q0 = wave * 2, q1 = q0 + 1;
#pragma unroll
        for (int c = 0; c < 12; ++c) {
            v0[c] = q_x[q0 * D + lane + 64 * c];
            v1[c] = q_x[q1 * D + lane + 64 * c];
            s0 += v0[c]; t0 = fmaf(v0[c], v0[c], t0);
            s1 += v1[c]; t1 = fmaf(v1[c], v1[c], t1);
        }
#pragma unroll
        for (int off = 32; off > 0; off >>= 1) {
            s0 += __shfl_xor(s0, off, 64);
            s1 += __shfl_xor(s1, off, 64);
            t0 += __shfl_xor(t0, off, 64);
            t1 += __shfl_xor(t1, off, 64);
        }
        const float m0 = s0 * (1.0f / D), m1 = s1 * (1.0f / D);
        const float r0 = rsqrtf(t0 * (1.0f / D) - m0 * m0 + EPS);
        const float r1 = rsqrtf(t1 * (1.0f / D) - m1 * m1 + EPS);
#pragma unroll
        for (int c = 0; c < 12; ++c) {
            qbf[q0][lane + 64 * c] = f2bf((v0[c] - m0) * r0 * wq[c] + bq[c]);
            qbf[q1][lane + 64 * c] = f2bf((v1[c] - m1) * r1 * wq[c] + bq[c]);
        }
    }

    // kv-LN -> tile (bf16) + register pack, rows 4w..4w+3 in 2 batches of 2.
    unsigned pk01[12], pk23[12];
#pragma unroll
    for (int b2 = 0; b2 < 2; ++b2) {
        const int nl0 = wave * 4 + 2 * b2;
        const int n0 = h * 16 + nl0, n1 = n0 + 1;
        const bool a0 = n0 < NP, a1 = n1 < NP;
        const float* x0 = kv_x + ((size_t)b * NP + n0) * D;
        const float* x1 = kv_x + ((size_t)b * NP + n1) * D;
        float v0[12], v1[12];
        float s0 = 0.f, t0 = 0.f, s1 = 0.f, t1 = 0.f;
#pragma unroll
        for (int c = 0; c < 12; ++c) {
            v0[c] = a0 ? x0[lane + 64 * c] : 0.f;
            v1[c] = a1 ? x1[lane + 64 * c] : 0.f;
            s0 += v0[c]; t0 = fmaf(v0[c], v0[c], t0);
            s1 += v1[c]; t1 = fmaf(v1[c], v1[c], t1);
        }
#pragma unroll
        for (int off = 32; off > 0; off >>= 1) {
            s0 += __shfl_xor(s0, off, 64);
            s1 += __shfl_xor(s1, off, 64);
            t0 += __shfl_xor(t0, off, 64);
            t1 += __shfl_xor(t1, off, 64);
        }
        const float m0 = s0 * (1.0f / D), m1 = s1 * (1.0f / D);
        const float r0 = rsqrtf(t0 * (1.0f / D) - m0 * m0 + EPS);
        const float r1 = rsqrtf(t1 * (1.0f / D) - m1 * m1 + EPS);
#pragma unroll
        for (int c = 0; c < 12; ++c) {
            const int d = lane + 64 * c;
            const unsigned short bf0 = a0 ? f2bf((v0[c] - m0) * r0 * wv[c] + bv[c]) : (unsigned short)0;
            const unsigned short bf1 = a1 ? f2bf((v1[c] - m1) * r1 * wv[c] + bv[c]) : (unsigned short)0;
            tile[nl0][d] = bf0;
            tile[nl0 + 1][d] = bf1;
            const unsigned packed = (unsigned)bf0 | ((unsigned)bf1 << 16);
            if (b2 == 0) pk01[c] = packed; else pk23[c] = packed;
        }
    }

    // direct frag store: 12 x 8B per thread, no LDS gather
    {
        const int kg = kgbase + (wave >> 1);
        const int eh = (wave & 1);
        const int dl = lane & 15;
#pragma unroll
        for (int c = 0; c < 12; ++c) {
            const int dt = (lane >> 4) + 4 * c;
            uint2 val; val.x = pk01[c]; val.y = pk23[c];
            *(uint2*)(kvTf + ((((size_t)b * 48 + dt) * KT + kt) * 64 + kg * 16 + dl) * 8 + eh * 4) = val;
        }
    }
    __syncthreads();

    // scores via MFMA: S16x8 = tile(16 x 768) x qbf^T, wave 0 only.
    if (live && wave == 0) {
        f32x4 s0 = {0.f, 0.f, 0.f, 0.f}, s1 = {0.f, 0.f, 0.f, 0.f};
        const int ar = lane & 15, akg = lane >> 4;
        const int qr = ar & 7;
#pragma unroll
        for (int k2 = 0; k2 < 24; k2 += 2) {
            s0 = __builtin_amdgcn_mfma_f32_16x16x32_bf16(
                *(const short8*)&tile[ar][k2 * 32 + akg * 8],
                *(const short8*)&qbf[qr][k2 * 32 + akg * 8], s0, 0, 0, 0);
            s1 = __builtin_amdgcn_mfma_f32_16x16x32_bf16(
                *(const short8*)&tile[ar][(k2 + 1) * 32 + akg * 8],
                *(const short8*)&qbf[qr][(k2 + 1) * 32 + akg * 8], s1, 0, 0, 0);
        }
        s0 = s0 + s1;
        const int q = lane & 15;
        if (q < NQ) {
#pragma unroll
            for (int reg = 0; reg < 4; ++reg) {
                const int n = h * 16 + akg * 4 + reg;
                if (n < NP) S[((size_t)b * NQ + q) * NP + n] = s0[reg] * INV_SQRT_D;
            }
        }
    }
}

// Softmax once per unordered pair u={i<j}: 16 rows r = dir*8+q
// (dir0 = softmax(S_i - S_j), dir1 = softmax(S_j - S_i)), written bf16 in
// MFMA-frag layout Abf[u][kt:7][slot:64][e:8], slot = kg*16 + r.
__global__ __launch_bounds__(512) void aprep(const float* __restrict__ S,
                                             unsigned short* __restrict__ Abf) {
    const int u = blockIdx.x;
    int uu = u, i = 0;
    while (uu >= 31 - i) { uu -= 31 - i; ++i; }
    const int j = i + 1 + uu;

    const int tid = threadIdx.x, wave = tid >> 6, lane = tid & 63;
    __shared__ unsigned short lrow[16][KP];  // 7 KB

    for (int jj = 0; jj < 2; ++jj) {
        const int r = wave * 2 + jj;          // 0..15
        const int dir = r >> 3, q = r & 7;
        const float* Sa = S + ((size_t)(dir ? j : i) * NQ + q) * NP;
        const float* Sb = S + ((size_t)(dir ? i : j) * NQ + q) * NP;
        float v[4];
        float m = -1e30f;
#pragma unroll
        for (int c = 0; c < 4; ++c) {
            const int n = lane + 64 * c;
            v[c] = (n < NP) ? (Sa[n] - Sb[n]) : -1e30f;
            m = fmaxf(m, v[c]);
        }
        m = wave_reduce_max(m);
        float e[4];
        float sum = 0.f;
#pragma unroll
        for (int c = 0; c < 4; ++c) {
            const int n = lane + 64 * c;
            e[c] = (n < NP) ? __expf(v[c] - m) : 0.f;
            sum += e[c];
        }
        sum = wave_reduce_sum(sum);
        const float rinv = 1.0f / sum;
#pragma unroll
        for (int c = 0; c < 4; ++c) {
            const int n = lane + 64 * c;
            if (n < KP) lrow[r][n] = (n < NP) ? f2bf(e[c] * rinv) : (unsigned short)0;
        }
    }
    __syncthreads();

    if (tid < 448) {
        const int kt = tid >> 6, slot = tid & 63;
        const int kg = slot >> 4, lr = slot & 15;
        const short8 vals = *(const short8*)(&lrow[lr][kt * 32 + kg * 8]);
        *(short8*)(Abf + (((size_t)u * KT + kt) * 64 + slot) * 8) = vals;
    }
}

// dgemm v4: 8-wave (512 thr) LDS-staged pair GEMM, 48 KB LDS -> 2 blocks/CU
// so one block's MFMA phase overlaps the other's staging drain.
// Block = (tile t, cs of 16): 48-col slice (3 dt). 8 waves.
//  t < 28 (off-diag, groups gi<gj): wave = (pi, bh): pairs (i=4gi+pi,
//    j=4gj+2bh) and (i, j+1), all 3 dt. Shared ki read: 9 reads/12 MFMAs.
//  t >= 28 (diag-combo): waves 0-5: 2 pairs each from the two 4-group
//    6-enums; waves 6,7 zero-fill the 8 diagonal outputs.
// acc = A@kv_i + (-A)@kv_j; rows dir0 -> out[i*B+j], dir1 -> -acc at [j*B+i].
__global__ __launch_bounds__(512, 4) void dgemm(const unsigned short* __restrict__ Abf,
                                                const unsigned short* __restrict__ kvTf,
                                                float* __restrict__ out) {
    const int bid = blockIdx.x;
    const int t = bid >> 4, cs = bid & 15;   // XCD = bid%8 = cs%8
    const int tid = threadIdx.x, wave = tid >> 6, lane = tid & 63;

    __shared__ unsigned short stg[2][8][3][64][8];  // 48 KB double-buffered

    const bool offd = (t < NTOFF);
    int gi = 0, gj = 0;
    if (offd) {
        int tt = t, a = 0;
        while (tt >= 7 - a) { tt -= 7 - a; ++a; }
        gi = a; gj = a + 1 + tt;
    }
    const int dbase = 8 * (t - NTOFF);

    // ---- wave decode: 2 pairs, all 3 dt ----
    int i0 = 0, j0 = 0, i1 = 0, j1 = 0;
    int p0i = 0, p0j = 0, p1i = 0, p1j = 0;
    bool compute = true;
    if (offd) {
        const int pi = wave >> 1, bh = wave & 1;
        i0 = 4 * gi + pi; j0 = 4 * gj + 2 * bh;
        i1 = i0;          j1 = j0 + 1;
        p0i = pi; p0j = 4 + 2 * bh; p1i = pi; p1j = p0j + 1;
    } else if (wave < 6) {
        const int g = wave / 3, k3 = wave - 3 * g;
        const int ea[6] = {0, 0, 0, 1, 1, 2}, eb[6] = {1, 2, 3, 2, 3, 3};
        const int e0 = 2 * k3, e1 = e0 + 1;
        p0i = 4 * g + ea[e0]; p0j = 4 * g + eb[e0];
        p1i = 4 * g + ea[e1]; p1j = 4 * g + eb[e1];
        i0 = dbase + p0i; j0 = dbase + p0j;
        i1 = dbase + p1i; j1 = dbase + p1j;
    } else {
        compute = false;
        const int zw = wave - 6;
#pragma unroll
        for (int t2 = 0; t2 < 4; ++t2) {
            const int ii = dbase + zw * 4 + t2;
            float* base = out + (size_t)(ii * B + ii) * NQ * D + cs * 48;
#pragma unroll
            for (int rep = 0; rep < 6; ++rep) {
                const int e = rep * 64 + lane;
                const int q = e / 48, c = e - q * 48;
                base[q * D + c] = 0.f;
            }
        }
    }

    // ---- A prefetch to registers (2 pairs x 7 KB) ----
    short8 areg0[KT], areg1[KT];
    if (compute) {
        const int u0 = (i0 * (63 - i0)) / 2 + (j0 - i0 - 1);
        const int u1 = (i1 * (63 - i1)) / 2 + (j1 - i1 - 1);
        const unsigned short* Au0 = Abf + (size_t)u0 * KT * 512 + (size_t)lane * 8;
        const unsigned short* Au1 = Abf + (size_t)u1 * KT * 512 + (size_t)lane * 8;
#pragma unroll
        for (int kt = 0; kt < KT; ++kt) {
            areg0[kt] = *(const short8*)(Au0 + (size_t)kt * 512);
            areg1[kt] = *(const short8*)(Au1 + (size_t)kt * 512);
        }
    }

    // ---- staging: wave stages panel sp = wave, dt 0..2 ----
    const int sp = wave;
    const int sb = offd ? ((sp < 4) ? (4 * gi + sp) : (4 * gj + sp - 4)) : (dbase + sp);
    const unsigned short* gbase =
        kvTf + (((size_t)sb * 48 + cs * 3) * KT) * 512 + (size_t)lane * 8;

    f32x4 acc0[3], acc1[3];
#pragma unroll
    for (int nf = 0; nf < 3; ++nf) {
        f32x4 z = {0.f, 0.f, 0.f, 0.f};
        acc0[nf] = z; acc1[nf] = z;
    }

#pragma unroll
    for (int r = 0; r < 3; ++r)
        __builtin_amdgcn_global_load_lds(
            (const __attribute__((address_space(1))) void*)(gbase + ((size_t)r * KT) * 512),
            (__attribute__((address_space(3))) void*)(&stg[0][sp][r][0][0]), 16, 0, 0);
    __syncthreads();

    int buf = 0;
    for (int kt = 0; kt < KT; ++kt) {
        if (kt + 1 < KT) {
#pragma unroll
            for (int r = 0; r < 3; ++r)
                __builtin_amdgcn_global_load_lds(
                    (const __attribute__((address_space(1))) void*)(gbase + ((size_t)r * KT + kt + 1) * 512),
                    (__attribute__((address_space(3))) void*)(&stg[buf ^ 1][sp][r][0][0]), 16, 0, 0);
        }
        if (compute) {
            const short8 a0 = areg0[kt], a1 = areg1[kt];
            short8 na0, na1;
#pragma unroll
            for (int e = 0; e < 8; ++e) {
                na0[e] = (short)(a0[e] ^ (short)0x8000);
                na1[e] = (short)(a1[e] ^ (short)0x8000);
            }
            if (offd) {  // shared ki: 9 ds_reads feed 12 MFMAs
#pragma unroll
                for (int nf = 0; nf < 3; ++nf) {
                    const short8 ki  = *(const short8*)(&stg[buf][p0i][nf][lane][0]);
                    const short8 kj0 = *(const short8*)(&stg[buf][p0j][nf][lane][0]);
                    const short8 kj1 = *(const short8*)(&stg[buf][p1j][nf][lane][0]);
                    acc0[nf] = __builtin_amdgcn_mfma_f32_16x16x32_bf16(a0,  ki,  acc0[nf], 0, 0, 0);
                    acc0[nf] = __builtin_amdgcn_mfma_f32_16x16x32_bf16(na0, kj0, acc0[nf], 0, 0, 0);
                    acc1[nf] = __builtin_amdgcn_mfma_f32_16x16x32_bf16(a1,  ki,  acc1[nf], 0, 0, 0);
                    acc1[nf] = __builtin_amdgcn_mfma_f32_16x16x32_bf16(na1, kj1, acc1[nf], 0, 0, 0);
                }
            } else {
#pragma unroll
                for (int nf = 0; nf < 3; ++nf) {
                    const short8 k0i = *(const short8*)(&stg[buf][p0i][nf][lane][0]);
                    const short8 k0j = *(const short8*)(&stg[buf][p0j][nf][lane][0]);
                    const short8 k1i = *(const short8*)(&stg[buf][p1i][nf][lane][0]);
                    const short8 k1j = *(const short8*)(&stg[buf][p1j][nf][lane][0]);
                    acc0[nf] = __builtin_amdgcn_mfma_f32_16x16x32_bf16(a0,  k0i, acc0[nf], 0, 0, 0);
                    acc0[nf] = __builtin_amdgcn_mfma_f32_16x16x32_bf16(na0, k0j, acc0[nf], 0, 0, 0);
                    acc1[nf] = __builtin_amdgcn_mfma_f32_16x16x32_bf16(a1,  k1i, acc1[nf], 0, 0, 0);
                    acc1[nf] = __builtin_amdgcn_mfma_f32_16x16x32_bf16(na1, k1j, acc1[nf], 0, 0, 0);
                }
            }
        }
        __syncthreads();
        buf ^= 1;
    }

    // ---- epilogue: C row-in-tile = (lane>>4)*4 + reg, col = lane&15 ----
    if (compute) {
        const int kgrp = lane >> 4, dl = lane & 15;
        const int colb = cs * 48 + dl;
#pragma unroll
        for (int pr = 0; pr < 2; ++pr) {
            const int i = pr ? i1 : i0, j = pr ? j1 : j0;
            const f32x4* acc = pr ? acc1 : acc0;
            const int pij = i * B + j, pji = j * B + i;
#pragma unroll
            for (int reg = 0; reg < 4; ++reg) {
                const int r = kgrp * 4 + reg;
                const int dirr = r >> 3, qq = r & 7;
                const int p = dirr ? pji : pij;
                const float sgn = dirr ? -1.f : 1.f;
                float* op = out + ((size_t)p * NQ + qq) * D + colb;
#pragma unroll
                for (int nf = 0; nf < 3; ++nf) op[nf * 16] = sgn * acc[nf][reg];
            }
        }
    }
}

extern "C" void kernel_launch(void* const* d_in, const int* in_sizes, int n_in,
                              void* d_out, int out_size, void* d_ws, size_t ws_size,
                              hipStream_t stream) {
    const float* q_x     = (const float*)d_in[0];
    const float* kv_x    = (const float*)d_in[1];
    const float* ln_q_w  = (const float*)d_in[2];
    const float* ln_q_b  = (const float*)d_in[3];
    const float* ln_kv_w = (const float*)d_in[4];
    const float* ln_kv_b = (const float*)d_in[5];
    float* out = (float*)d_out;

    float* ws = (float*)d_ws;
    float* S  = ws;                                             // 32*8*196 f32
    unsigned short* kvTf = (unsigned short*)(ws + B * NQ * NP);  // 32*48*7*512 bf16
    unsigned short* Abf  = kvTf + (size_t)B * 48 * KT * 512;     // 496*7*512 bf16

    kv_fused<<<B * 14, 256, 0, stream>>>(q_x, ln_q_w, ln_q_b, kv_x, ln_kv_w, ln_kv_b, S, kvTf);
    aprep<<<(B * (B - 1)) / 2, 512, 0, stream>>>(S, Abf);
    dgemm<<<NTILES * 16, 512, 0, stream>>>(Abf, kvTf, out);
}